// Round 3
// baseline (27858.276 us; speedup 1.0000x reference)
//
#include <hip/hip_runtime.h>
#include <hip/hip_bf16.h>

#define NSTEP 119
#define BM 16

// ws layout (float indices)
#define OFF_Z2H   0u
#define OFF_WIH0  98304u
#define OFF_WHH0  147456u
#define OFF_WIH1  344064u
#define OFF_WHH1  540672u
#define OFF_WIH2  737280u
#define OFF_WHH2  933888u
#define OFF_OUTW  1130496u
#define OFF_B     1146880u
#define OFF_BZ2H  (OFF_B)
#define OFF_BIH0  (OFF_B+768u)
#define OFF_BHH0  (OFF_B+1536u)
#define OFF_BIH1  (OFF_B+2304u)
#define OFF_BHH1  (OFF_B+3072u)
#define OFF_BIH2  (OFF_B+3840u)
#define OFF_BHH2  (OFF_B+4608u)
#define OFF_OUTB  (OFF_B+5376u)
#define OFF_FLAG  (OFF_B+5440u)   // int: 1 = device buffers are bf16

// ---- dtype auto-detect: fp32-world byte1 is uniform mantissa bits; bf16-world
// byte1 is the high byte of a small-magnitude bf16 (exp-ish in [0x38,0x3E]). ----
__global__ void detect_dtype(const void* z2hb, int* flag) {
  if (threadIdx.x == 0) {
    const unsigned* u = (const unsigned*)z2hb;
    int hits = 0;
    for (int i = 0; i < 32; ++i) {
      unsigned e = (u[i] >> 8) & 0x7F;
      if (e >= 0x38 && e <= 0x3E) ++hits;
    }
    *flag = (hits >= 16) ? 1 : 0;
  }
}

// W[R][K] (row-major) -> T[k4][r][c] = W[r][4*k4+c]  (float4-coalesced GEMV layout)
__global__ void conv_transpose(const void* __restrict__ src, float* __restrict__ dst,
                               int R, int K, const int* __restrict__ flag) {
  int idx = blockIdx.x * 256 + threadIdx.x;
  if (idx >= R * K) return;
  int r = idx / K, k = idx - r * K;
  float v = (*flag) ? (float)((const __hip_bfloat16*)src)[idx] : ((const float*)src)[idx];
  dst[((size_t)(k >> 2) * R + r) * 4 + (k & 3)] = v;
}

__global__ void conv_copy(const void* __restrict__ src, float* __restrict__ dst,
                          int n, const int* __restrict__ flag) {
  int idx = blockIdx.x * 256 + threadIdx.x;
  if (idx >= n) return;
  dst[idx] = (*flag) ? (float)((const __hip_bfloat16*)src)[idx] : ((const float*)src)[idx];
}

__device__ __forceinline__ void dot4(float& acc, const float4 w, const float4 v) {
  acc += w.x * v.x + w.y * v.y + w.z * v.z + w.w * v.w;
}

// One GRU layer. Thread = (wave, half, jl): j = wave*32+jl owns neuron j;
// halves split K, reduced via shfl_xor(32). hcur updated in place.
__device__ __forceinline__ void gru_layer(
    float (*hcur)[260], const float* __restrict__ Xin, int xld,
    const float4* __restrict__ WiT, int ki4,
    const float4* __restrict__ WhT,
    const float* __restrict__ bih, const float* __restrict__ bhh,
    int j, int half)
{
  float ar[16], az[16], ain[16], ahn[16];
  #pragma unroll
  for (int m = 0; m < 16; ++m) { ar[m] = 0.f; az[m] = 0.f; ain[m] = 0.f; ahn[m] = 0.f; }

  {
    const int kb = half * (ki4 >> 1), ke = kb + (ki4 >> 1);
    #pragma unroll 2
    for (int k4 = kb; k4 < ke; ++k4) {
      float4 w0 = WiT[(size_t)k4 * 768 + j];
      float4 w1 = WiT[(size_t)k4 * 768 + 256 + j];
      float4 w2 = WiT[(size_t)k4 * 768 + 512 + j];
      #pragma unroll
      for (int m = 0; m < 16; ++m) {
        float4 x4 = *(const float4*)(Xin + m * xld + k4 * 4);
        dot4(ar[m], w0, x4);
        dot4(az[m], w1, x4);
        dot4(ain[m], w2, x4);
      }
    }
  }
  {
    const int kb = half * 32, ke = kb + 32;
    #pragma unroll 2
    for (int k4 = kb; k4 < ke; ++k4) {
      float4 w0 = WhT[(size_t)k4 * 768 + j];
      float4 w1 = WhT[(size_t)k4 * 768 + 256 + j];
      float4 w2 = WhT[(size_t)k4 * 768 + 512 + j];
      #pragma unroll
      for (int m = 0; m < 16; ++m) {
        float4 x4 = *(const float4*)(&hcur[m][k4 * 4]);
        dot4(ar[m], w0, x4);
        dot4(az[m], w1, x4);
        dot4(ahn[m], w2, x4);
      }
    }
  }
  __syncthreads();   // all reads of hcur complete

  const float b_r  = bih[j] + bhh[j];
  const float b_z  = bih[256 + j] + bhh[256 + j];
  const float b_in = bih[512 + j];
  const float b_hn = bhh[512 + j];
  #pragma unroll
  for (int i = 0; i < 8; ++i) {
    float sr0 = ar[i]     + __shfl_xor(ar[i], 32);
    float sr1 = ar[8 + i] + __shfl_xor(ar[8 + i], 32);
    float sz0 = az[i]     + __shfl_xor(az[i], 32);
    float sz1 = az[8 + i] + __shfl_xor(az[8 + i], 32);
    float si0 = ain[i]     + __shfl_xor(ain[i], 32);
    float si1 = ain[8 + i] + __shfl_xor(ain[8 + i], 32);
    float sh0 = ahn[i]     + __shfl_xor(ahn[i], 32);
    float sh1 = ahn[8 + i] + __shfl_xor(ahn[8 + i], 32);
    const int m = half * 8 + i;
    float tar = (half ? sr1 : sr0) + b_r;
    float taz = (half ? sz1 : sz0) + b_z;
    float tai = (half ? si1 : si0) + b_in;
    float tah = (half ? sh1 : sh0) + b_hn;
    float rg = 1.f / (1.f + expf(-tar));
    float zg = 1.f / (1.f + expf(-taz));
    float ng = tanhf(tai + rg * tah);
    hcur[m][j] = (1.f - zg) * ng + zg * hcur[m][j];
  }
  __syncthreads();   // hcur updated
}

__global__ __launch_bounds__(512)
void moldec_main(const void* __restrict__ zin, const void* __restrict__ embin,
                 const float* __restrict__ ws, void* __restrict__ outv)
{
  __shared__ float hF[3][16][260];
  __shared__ float xF[16][132];   // also z-staging in init
  __shared__ float logS[16][66];
  __shared__ int tokS[16];

  const int tid = threadIdx.x;
  const int wave = tid >> 6, lane = tid & 63;
  const int half = lane >> 5;
  const int j = wave * 32 + (lane & 31);
  const int b0 = blockIdx.x * BM;
  const int isbf = ((const int*)ws)[OFF_FLAG];

  // ---- stage z rows ----
  {
    const int m = tid >> 5, e = tid & 31;
    #pragma unroll
    for (int t = 0; t < 4; ++t) {
      int col = e + t * 32;
      float v;
      if (isbf) v = (float)((const __hip_bfloat16*)zin)[(size_t)(b0 + m) * 128 + col];
      else      v = ((const float*)zin)[(size_t)(b0 + m) * 128 + col];
      xF[m][col] = v;
    }
    if (tid < 16) tokS[tid] = 1;
  }
  __syncthreads();

  // ---- h0 = tanh(z @ z2h_w.T + b) ----
  {
    const float4* Z2T = (const float4*)(ws + OFF_Z2H);
    const float* bz = ws + OFF_BZ2H;
    for (int c = tid; c < 768; c += 512) {
      float acc[16];
      #pragma unroll
      for (int m = 0; m < 16; ++m) acc[m] = 0.f;
      for (int k4 = 0; k4 < 32; ++k4) {
        float4 w = Z2T[(size_t)k4 * 768 + c];
        #pragma unroll
        for (int m = 0; m < 16; ++m) {
          float4 x4 = *(const float4*)(&xF[m][k4 * 4]);
          dot4(acc[m], w, x4);
        }
      }
      float b = bz[c];
      int lay = c >> 8, cj = c & 255;
      #pragma unroll
      for (int m = 0; m < 16; ++m)
        hF[lay][m][cj] = tanhf(acc[m] + b);
    }
  }
  __syncthreads();

  for (int step = 0; step < NSTEP; ++step) {
    // ---- x = emb[tok] ----
    {
      const int m = tid >> 5, e = tid & 31;
      const int tk = tokS[m];
      if (isbf) {
        xF[m][e]      = (float)((const __hip_bfloat16*)embin)[tk * 64 + e];
        xF[m][e + 32] = (float)((const __hip_bfloat16*)embin)[tk * 64 + e + 32];
      } else {
        xF[m][e]      = ((const float*)embin)[tk * 64 + e];
        xF[m][e + 32] = ((const float*)embin)[tk * 64 + e + 32];
      }
    }
    __syncthreads();

    gru_layer(hF[0], &xF[0][0],    132, (const float4*)(ws + OFF_WIH0), 16,
              (const float4*)(ws + OFF_WHH0), ws + OFF_BIH0, ws + OFF_BHH0, j, half);
    gru_layer(hF[1], &hF[0][0][0], 260, (const float4*)(ws + OFF_WIH1), 64,
              (const float4*)(ws + OFF_WHH1), ws + OFF_BIH1, ws + OFF_BHH1, j, half);
    gru_layer(hF[2], &hF[1][0][0], 260, (const float4*)(ws + OFF_WIH2), 64,
              (const float4*)(ws + OFF_WHH2), ws + OFF_BIH2, ws + OFF_BHH2, j, half);

    // ---- logits: wave w owns rows 2w,2w+1; lane = vocab col ----
    {
      const float4* OT = (const float4*)(ws + OFF_OUTW);
      const int m0 = wave * 2;
      float a0 = 0.f, a1 = 0.f;
      for (int k4 = 0; k4 < 64; ++k4) {
        float4 w = OT[(size_t)k4 * 64 + lane];
        float4 x0 = *(const float4*)(&hF[2][m0][k4 * 4]);
        float4 x1 = *(const float4*)(&hF[2][m0 + 1][k4 * 4]);
        dot4(a0, w, x0);
        dot4(a1, w, x1);
      }
      float ob = ws[OFF_OUTB + lane];
      a0 += ob; a1 += ob;
      logS[m0][lane] = a0;
      logS[m0 + 1][lane] = a1;
      const size_t o0 = ((size_t)(b0 + m0) * NSTEP + step) * 64 + lane;
      const size_t o1 = ((size_t)(b0 + m0 + 1) * NSTEP + step) * 64 + lane;
      if (isbf) {
        ((__hip_bfloat16*)outv)[o0] = (__hip_bfloat16)a0;
        ((__hip_bfloat16*)outv)[o1] = (__hip_bfloat16)a1;
      } else {
        ((float*)outv)[o0] = a0;
        ((float*)outv)[o1] = a1;
      }
    }
    __syncthreads();

    // ---- argmax (first-max, matches jnp.argmax) ----
    if (tid < 16) {
      float best = logS[tid][0]; int bj = 0;
      for (int j2 = 1; j2 < 64; ++j2) {
        float v = logS[tid][j2];
        if (v > best) { best = v; bj = j2; }
      }
      tokS[tid] = bj;
    }
    __syncthreads();
  }
}

extern "C" void kernel_launch(void* const* d_in, const int* in_sizes, int n_in,
                              void* d_out, int out_size, void* d_ws, size_t ws_size,
                              hipStream_t stream) {
  float* ws = (float*)d_ws;
  int* flag = (int*)(ws + OFF_FLAG);

  detect_dtype<<<1, 64, 0, stream>>>(d_in[3], flag);

  conv_transpose<<<384, 256, 0, stream>>>(d_in[2],  ws + OFF_Z2H,  768, 128, flag);
  conv_transpose<<<192, 256, 0, stream>>>(d_in[6],  ws + OFF_WIH0, 768, 64,  flag);
  conv_transpose<<<768, 256, 0, stream>>>(d_in[7],  ws + OFF_WHH0, 768, 256, flag);
  conv_transpose<<<768, 256, 0, stream>>>(d_in[10], ws + OFF_WIH1, 768, 256, flag);
  conv_transpose<<<768, 256, 0, stream>>>(d_in[11], ws + OFF_WHH1, 768, 256, flag);
  conv_transpose<<<768, 256, 0, stream>>>(d_in[14], ws + OFF_WIH2, 768, 256, flag);
  conv_transpose<<<768, 256, 0, stream>>>(d_in[15], ws + OFF_WHH2, 768, 256, flag);
  conv_transpose<<<64,  256, 0, stream>>>(d_in[4],  ws + OFF_OUTW, 64,  256, flag);

  conv_copy<<<3, 256, 0, stream>>>(d_in[3],  ws + OFF_BZ2H, 768, flag);
  conv_copy<<<3, 256, 0, stream>>>(d_in[8],  ws + OFF_BIH0, 768, flag);
  conv_copy<<<3, 256, 0, stream>>>(d_in[9],  ws + OFF_BHH0, 768, flag);
  conv_copy<<<3, 256, 0, stream>>>(d_in[12], ws + OFF_BIH1, 768, flag);
  conv_copy<<<3, 256, 0, stream>>>(d_in[13], ws + OFF_BHH1, 768, flag);
  conv_copy<<<3, 256, 0, stream>>>(d_in[16], ws + OFF_BIH2, 768, flag);
  conv_copy<<<3, 256, 0, stream>>>(d_in[17], ws + OFF_BHH2, 768, flag);
  conv_copy<<<1, 64,  0, stream>>>(d_in[5],  ws + OFF_OUTB, 64,  flag);

  moldec_main<<<256, 512, 0, stream>>>(d_in[0], d_in[1], ws, d_out);
}

// Round 4
// 27839.789 us; speedup vs baseline: 1.0007x; 1.0007x over previous
//
#include <hip/hip_runtime.h>
#include <hip/hip_bf16.h>

typedef __bf16 bf16;
typedef __bf16 bf16x8 __attribute__((ext_vector_type(8)));
typedef float  f32x4  __attribute__((ext_vector_type(4)));

#define MFMA16(a,b,c) __builtin_amdgcn_mfma_f32_16x16x32_bf16((a),(b),(c),0,0,0)

#define NSTEP 119
#define BM 16

// ws layout (float indices) -- used by the fp32 fallback world
#define OFF_Z2H   0u
#define OFF_WIH0  98304u
#define OFF_WHH0  147456u
#define OFF_WIH1  344064u
#define OFF_WHH1  540672u
#define OFF_WIH2  737280u
#define OFF_WHH2  933888u
#define OFF_OUTW  1130496u
#define OFF_B     1146880u
#define OFF_BZ2H  (OFF_B)
#define OFF_BIH0  (OFF_B+768u)
#define OFF_BHH0  (OFF_B+1536u)
#define OFF_BIH1  (OFF_B+2304u)
#define OFF_BHH1  (OFF_B+3072u)
#define OFF_BIH2  (OFF_B+3840u)
#define OFF_BHH2  (OFF_B+4608u)
#define OFF_OUTB  (OFF_B+5376u)
#define OFF_FLAG  (OFF_B+5440u)   // int: 1 = device buffers are bf16

__device__ __forceinline__ f32x4 splat4(float v) { f32x4 r = {v, v, v, v}; return r; }

// ---- dtype auto-detect (see R2 notes): bf16 high bytes cluster in [0x38,0x3E] ----
__global__ void detect_dtype(const void* z2hb, int* flag) {
  if (threadIdx.x == 0) {
    const unsigned* u = (const unsigned*)z2hb;
    int hits = 0;
    for (int i = 0; i < 32; ++i) {
      unsigned e = (u[i] >> 8) & 0x7F;
      if (e >= 0x38 && e <= 0x3E) ++hits;
    }
    *flag = (hits >= 16) ? 1 : 0;
  }
}

// ================= fp32 fallback world (flag==0) =================
__global__ void conv_transpose(const void* __restrict__ src, float* __restrict__ dst,
                               int R, int K, const int* __restrict__ flag) {
  if (*flag) return;
  int idx = blockIdx.x * 256 + threadIdx.x;
  if (idx >= R * K) return;
  int r = idx / K, k = idx - r * K;
  float v = ((const float*)src)[idx];
  dst[((size_t)(k >> 2) * R + r) * 4 + (k & 3)] = v;
}

__global__ void conv_copy(const void* __restrict__ src, float* __restrict__ dst,
                          int n, const int* __restrict__ flag) {
  if (*flag) return;
  int idx = blockIdx.x * 256 + threadIdx.x;
  if (idx >= n) return;
  dst[idx] = ((const float*)src)[idx];
}

__device__ __forceinline__ void dot4(float& acc, const float4 w, const float4 v) {
  acc += w.x * v.x + w.y * v.y + w.z * v.z + w.w * v.w;
}

__device__ __forceinline__ void gru_layer(
    float (*hcur)[260], const float* __restrict__ Xin, int xld,
    const float4* __restrict__ WiT, int ki4,
    const float4* __restrict__ WhT,
    const float* __restrict__ bih, const float* __restrict__ bhh,
    int j, int half)
{
  float ar[16], az[16], ain[16], ahn[16];
  #pragma unroll
  for (int m = 0; m < 16; ++m) { ar[m] = 0.f; az[m] = 0.f; ain[m] = 0.f; ahn[m] = 0.f; }
  {
    const int kb = half * (ki4 >> 1), ke = kb + (ki4 >> 1);
    #pragma unroll 2
    for (int k4 = kb; k4 < ke; ++k4) {
      float4 w0 = WiT[(size_t)k4 * 768 + j];
      float4 w1 = WiT[(size_t)k4 * 768 + 256 + j];
      float4 w2 = WiT[(size_t)k4 * 768 + 512 + j];
      #pragma unroll
      for (int m = 0; m < 16; ++m) {
        float4 x4 = *(const float4*)(Xin + m * xld + k4 * 4);
        dot4(ar[m], w0, x4); dot4(az[m], w1, x4); dot4(ain[m], w2, x4);
      }
    }
  }
  {
    const int kb = half * 32, ke = kb + 32;
    #pragma unroll 2
    for (int k4 = kb; k4 < ke; ++k4) {
      float4 w0 = WhT[(size_t)k4 * 768 + j];
      float4 w1 = WhT[(size_t)k4 * 768 + 256 + j];
      float4 w2 = WhT[(size_t)k4 * 768 + 512 + j];
      #pragma unroll
      for (int m = 0; m < 16; ++m) {
        float4 x4 = *(const float4*)(&hcur[m][k4 * 4]);
        dot4(ar[m], w0, x4); dot4(az[m], w1, x4); dot4(ahn[m], w2, x4);
      }
    }
  }
  __syncthreads();
  const float b_r  = bih[j] + bhh[j];
  const float b_z  = bih[256 + j] + bhh[256 + j];
  const float b_in = bih[512 + j];
  const float b_hn = bhh[512 + j];
  #pragma unroll
  for (int i = 0; i < 8; ++i) {
    float sr0 = ar[i]     + __shfl_xor(ar[i], 32);
    float sr1 = ar[8 + i] + __shfl_xor(ar[8 + i], 32);
    float sz0 = az[i]     + __shfl_xor(az[i], 32);
    float sz1 = az[8 + i] + __shfl_xor(az[8 + i], 32);
    float si0 = ain[i]     + __shfl_xor(ain[i], 32);
    float si1 = ain[8 + i] + __shfl_xor(ain[8 + i], 32);
    float sh0 = ahn[i]     + __shfl_xor(ahn[i], 32);
    float sh1 = ahn[8 + i] + __shfl_xor(ahn[8 + i], 32);
    const int m = half * 8 + i;
    float tar = (half ? sr1 : sr0) + b_r;
    float taz = (half ? sz1 : sz0) + b_z;
    float tai = (half ? si1 : si0) + b_in;
    float tah = (half ? sh1 : sh0) + b_hn;
    float rg = 1.f / (1.f + expf(-tar));
    float zg = 1.f / (1.f + expf(-taz));
    float ng = tanhf(tai + rg * tah);
    hcur[m][j] = (1.f - zg) * ng + zg * hcur[m][j];
  }
  __syncthreads();
}

__global__ __launch_bounds__(512)
void moldec_main(const void* __restrict__ zin, const void* __restrict__ embin,
                 const float* __restrict__ ws, void* __restrict__ outv)
{
  const int isbf = ((const int*)(ws + OFF_FLAG))[0];
  if (isbf) return;   // bf16 world handled by MFMA kernel

  __shared__ float hF[3][16][260];
  __shared__ float xF[16][132];
  __shared__ float logS[16][66];
  __shared__ int tokS[16];

  const int tid = threadIdx.x;
  const int wave = tid >> 6, lane = tid & 63;
  const int half = lane >> 5;
  const int j = wave * 32 + (lane & 31);
  const int b0 = blockIdx.x * BM;

  {
    const int m = tid >> 5, e = tid & 31;
    #pragma unroll
    for (int t = 0; t < 4; ++t) {
      int col = e + t * 32;
      xF[m][col] = ((const float*)zin)[(size_t)(b0 + m) * 128 + col];
    }
    if (tid < 16) tokS[tid] = 1;
  }
  __syncthreads();

  {
    const float4* Z2T = (const float4*)(ws + OFF_Z2H);
    const float* bz = ws + OFF_BZ2H;
    for (int c = tid; c < 768; c += 512) {
      float acc[16];
      #pragma unroll
      for (int m = 0; m < 16; ++m) acc[m] = 0.f;
      for (int k4 = 0; k4 < 32; ++k4) {
        float4 w = Z2T[(size_t)k4 * 768 + c];
        #pragma unroll
        for (int m = 0; m < 16; ++m) {
          float4 x4 = *(const float4*)(&xF[m][k4 * 4]);
          dot4(acc[m], w, x4);
        }
      }
      float b = bz[c];
      int lay = c >> 8, cj = c & 255;
      #pragma unroll
      for (int m = 0; m < 16; ++m)
        hF[lay][m][cj] = tanhf(acc[m] + b);
    }
  }
  __syncthreads();

  for (int step = 0; step < NSTEP; ++step) {
    {
      const int m = tid >> 5, e = tid & 31;
      const int tk = tokS[m];
      xF[m][e]      = ((const float*)embin)[tk * 64 + e];
      xF[m][e + 32] = ((const float*)embin)[tk * 64 + e + 32];
    }
    __syncthreads();

    gru_layer(hF[0], &xF[0][0],    132, (const float4*)(ws + OFF_WIH0), 16,
              (const float4*)(ws + OFF_WHH0), ws + OFF_BIH0, ws + OFF_BHH0, j, half);
    gru_layer(hF[1], &hF[0][0][0], 260, (const float4*)(ws + OFF_WIH1), 64,
              (const float4*)(ws + OFF_WHH1), ws + OFF_BIH1, ws + OFF_BHH1, j, half);
    gru_layer(hF[2], &hF[1][0][0], 260, (const float4*)(ws + OFF_WIH2), 64,
              (const float4*)(ws + OFF_WHH2), ws + OFF_BIH2, ws + OFF_BHH2, j, half);

    {
      const float4* OT = (const float4*)(ws + OFF_OUTW);
      const int m0 = wave * 2;
      float a0 = 0.f, a1 = 0.f;
      for (int k4 = 0; k4 < 64; ++k4) {
        float4 w = OT[(size_t)k4 * 64 + lane];
        float4 x0 = *(const float4*)(&hF[2][m0][k4 * 4]);
        float4 x1 = *(const float4*)(&hF[2][m0 + 1][k4 * 4]);
        dot4(a0, w, x0); dot4(a1, w, x1);
      }
      float ob = ws[OFF_OUTB + lane];
      a0 += ob; a1 += ob;
      logS[m0][lane] = a0;
      logS[m0 + 1][lane] = a1;
      ((float*)outv)[((size_t)(b0 + m0) * NSTEP + step) * 64 + lane] = a0;
      ((float*)outv)[((size_t)(b0 + m0 + 1) * NSTEP + step) * 64 + lane] = a1;
    }
    __syncthreads();

    if (tid < 16) {
      float best = logS[tid][0]; int bj = 0;
      for (int j2 = 1; j2 < 64; ++j2) {
        float v = logS[tid][j2];
        if (v > best) { best = v; bj = j2; }
      }
      tokS[tid] = bj;
    }
    __syncthreads();
  }
}

// ================= bf16 MFMA world (flag==1) =================

__device__ __forceinline__ void bias6b(f32x4 acc[6], const bf16* __restrict__ b,
                                       int j0, int r15) {
  #pragma unroll
  for (int t = 0; t < 6; ++t)
    acc[t] = splat4((float)b[j0 + (t >> 1) * 256 + (t & 1) * 16 + r15]);
}

// acc[6] += A(16xK)*W^T, A in 1..3 bf16 components (LDS), B loaded once, reused.
template<int KT, int NC>
__device__ __forceinline__ void gemm6m(f32x4 acc[6],
    const bf16* __restrict__ A0, const bf16* __restrict__ A1,
    const bf16* __restrict__ A2, const int Ald,
    const bf16* __restrict__ W, const int Wld,
    const int j0, const int q, const int r15)
{
  #pragma unroll 2
  for (int kt = 0; kt < KT; ++kt) {
    const int ao = r15 * Ald + kt * 32 + q * 8;
    bf16x8 a0 = *(const bf16x8*)(A0 + ao);
    bf16x8 a1, a2;
    if constexpr (NC > 1) a1 = *(const bf16x8*)(A1 + ao);
    if constexpr (NC > 2) a2 = *(const bf16x8*)(A2 + ao);
    bf16x8 bb[6];
    #pragma unroll
    for (int t = 0; t < 6; ++t)
      bb[t] = *(const bf16x8*)(W + (size_t)(j0 + (t >> 1) * 256 + (t & 1) * 16 + r15) * Wld
                               + kt * 32 + q * 8);
    #pragma unroll
    for (int t = 0; t < 6; ++t) acc[t] = MFMA16(a0, bb[t], acc[t]);
    if constexpr (NC > 1) {
      #pragma unroll
      for (int t = 0; t < 6; ++t) acc[t] = MFMA16(a1, bb[t], acc[t]);
    }
    if constexpr (NC > 2) {
      #pragma unroll
      for (int t = 0; t < 6; ++t) acc[t] = MFMA16(a2, bb[t], acc[t]);
    }
  }
}

__device__ __forceinline__ void split3(float hv, bf16& c0, bf16& c1, bf16& c2) {
  c0 = (bf16)hv;        float r1 = hv - (float)c0;
  c1 = (bf16)r1;        float r2 = r1 - (float)c1;
  c2 = (bf16)r2;
}

__device__ __forceinline__ void gates_update3(const f32x4 ai[6], const f32x4 ah[6],
    bf16 (*h0)[264], bf16 (*h1)[264], bf16 (*h2)[264],
    const int j0, const int q, const int r15)
{
  #pragma unroll
  for (int s = 0; s < 2; ++s) {
    const int j = j0 + s * 16 + r15;
    #pragma unroll
    for (int r = 0; r < 4; ++r) {
      const int m = q * 4 + r;
      float rg = 1.f / (1.f + expf(-(ai[s][r]     + ah[s][r])));
      float zg = 1.f / (1.f + expf(-(ai[2 + s][r] + ah[2 + s][r])));
      float ng = tanhf(ai[4 + s][r] + rg * ah[4 + s][r]);
      float hp = (float)h0[m][j] + (float)h1[m][j] + (float)h2[m][j];
      float hv = (1.f - zg) * ng + zg * hp;
      bf16 c0, c1, c2;
      split3(hv, c0, c1, c2);
      h0[m][j] = c0; h1[m][j] = c1; h2[m][j] = c2;
    }
  }
}

__global__ __launch_bounds__(512)
void moldec_mfma(const bf16* __restrict__ z,     const bf16* __restrict__ emb,
                 const bf16* __restrict__ z2h_w, const bf16* __restrict__ z2h_b,
                 const bf16* __restrict__ out_w, const bf16* __restrict__ out_b,
                 const bf16* __restrict__ wih0, const bf16* __restrict__ whh0,
                 const bf16* __restrict__ bih0, const bf16* __restrict__ bhh0,
                 const bf16* __restrict__ wih1, const bf16* __restrict__ whh1,
                 const bf16* __restrict__ bih1, const bf16* __restrict__ bhh1,
                 const bf16* __restrict__ wih2, const bf16* __restrict__ whh2,
                 const bf16* __restrict__ bih2, const bf16* __restrict__ bhh2,
                 const float* __restrict__ ws, bf16* __restrict__ out)
{
  if (((const int*)(ws + OFF_FLAG))[0] == 0) return;  // fp32 world -> fallback kernel

  __shared__ __align__(16) bf16 hS[3][3][16][264];  // [layer][comp][m][j]
  __shared__ __align__(16) bf16 xS[16][72];
  __shared__ float logS[16][66];
  __shared__ int tokS[16];

  const int tid  = threadIdx.x;
  const int wave = tid >> 6;
  const int lane = tid & 63;
  const int q    = lane >> 4;
  const int r15  = lane & 15;
  const int b0   = blockIdx.x * BM;
  const int j0   = wave * 32;

  // ---- h0 = tanh(z @ z2h_w.T + b); z, z2h_w are exact bf16 (1-pass) ----
  {
    f32x4 acc[6];
    #pragma unroll
    for (int t = 0; t < 6; ++t)
      acc[t] = splat4((float)z2h_b[wave * 96 + t * 16 + r15]);
    #pragma unroll 2
    for (int kt = 0; kt < 4; ++kt) {
      bf16x8 a = *(const bf16x8*)(z + (size_t)(b0 + r15) * 128 + kt * 32 + q * 8);
      #pragma unroll
      for (int t = 0; t < 6; ++t) {
        const int col = wave * 96 + t * 16 + r15;
        bf16x8 b = *(const bf16x8*)(z2h_w + (size_t)col * 128 + kt * 32 + q * 8);
        acc[t] = MFMA16(a, b, acc[t]);
      }
    }
    #pragma unroll
    for (int t = 0; t < 6; ++t) {
      const int col = wave * 96 + t * 16 + r15;
      const int lay = col >> 8, j = col & 255;
      #pragma unroll
      for (int r = 0; r < 4; ++r) {
        const int m = q * 4 + r;
        float hv = tanhf(acc[t][r]);
        bf16 c0, c1, c2;
        split3(hv, c0, c1, c2);
        hS[lay][0][m][j] = c0; hS[lay][1][m][j] = c1; hS[lay][2][m][j] = c2;
      }
    }
    if (tid < 16) tokS[tid] = 1;
  }
  __syncthreads();

  for (int step = 0; step < NSTEP; ++step) {
    // ---- x = emb[tok] (exact bf16) ----
    if (tid < 128) {
      const int m = tid >> 3, e8 = (tid & 7) * 8;
      const int tk = tokS[m];
      *(bf16x8*)(&xS[m][e8]) = *(const bf16x8*)(emb + (size_t)tk * 64 + e8);
    }
    __syncthreads();

    // ---- layer 0 ----
    {
      f32x4 ai[6], ah[6];
      bias6b(ai, bih0, j0, r15);
      bias6b(ah, bhh0, j0, r15);
      gemm6m<2, 1>(ai, &xS[0][0], nullptr, nullptr, 72, wih0, 64, j0, q, r15);
      gemm6m<8, 3>(ah, &hS[0][0][0][0], &hS[0][1][0][0], &hS[0][2][0][0], 264,
                   whh0, 256, j0, q, r15);
      __syncthreads();
      gates_update3(ai, ah, hS[0][0], hS[0][1], hS[0][2], j0, q, r15);
    }
    __syncthreads();

    // ---- layer 1 ----
    {
      f32x4 ai[6], ah[6];
      bias6b(ai, bih1, j0, r15);
      bias6b(ah, bhh1, j0, r15);
      gemm6m<8, 3>(ai, &hS[0][0][0][0], &hS[0][1][0][0], &hS[0][2][0][0], 264,
                   wih1, 256, j0, q, r15);
      gemm6m<8, 3>(ah, &hS[1][0][0][0], &hS[1][1][0][0], &hS[1][2][0][0], 264,
                   whh1, 256, j0, q, r15);
      __syncthreads();
      gates_update3(ai, ah, hS[1][0], hS[1][1], hS[1][2], j0, q, r15);
    }
    __syncthreads();

    // ---- layer 2 ----
    {
      f32x4 ai[6], ah[6];
      bias6b(ai, bih2, j0, r15);
      bias6b(ah, bhh2, j0, r15);
      gemm6m<8, 3>(ai, &hS[1][0][0][0], &hS[1][1][0][0], &hS[1][2][0][0], 264,
                   wih2, 256, j0, q, r15);
      gemm6m<8, 3>(ah, &hS[2][0][0][0], &hS[2][1][0][0], &hS[2][2][0][0], 264,
                   whh2, 256, j0, q, r15);
      __syncthreads();
      gates_update3(ai, ah, hS[2][0], hS[2][1], hS[2][2], j0, q, r15);
    }
    __syncthreads();

    // ---- logits (waves 0-3, 16 cols each) ----
    if (wave < 4) {
      const int col = wave * 16 + r15;
      f32x4 acc = splat4((float)out_b[col]);
      #pragma unroll 2
      for (int kt = 0; kt < 8; ++kt) {
        const int ao = r15 * 264 + kt * 32 + q * 8;
        bf16x8 a0 = *(const bf16x8*)(&hS[2][0][0][0] + ao);
        bf16x8 a1 = *(const bf16x8*)(&hS[2][1][0][0] + ao);
        bf16x8 a2 = *(const bf16x8*)(&hS[2][2][0][0] + ao);
        bf16x8 b  = *(const bf16x8*)(out_w + (size_t)col * 256 + kt * 32 + q * 8);
        acc = MFMA16(a0, b, acc);
        acc = MFMA16(a1, b, acc);
        acc = MFMA16(a2, b, acc);
      }
      #pragma unroll
      for (int r = 0; r < 4; ++r) {
        const int m = q * 4 + r;
        logS[m][col] = acc[r];
        out[((size_t)(b0 + m) * NSTEP + step) * 64 + col] = (bf16)acc[r];
      }
    }
    __syncthreads();

    // ---- argmax (first-max semantics) ----
    if (tid < 16) {
      float best = logS[tid][0]; int bj = 0;
      for (int j2 = 1; j2 < 64; ++j2) {
        float v = logS[tid][j2];
        if (v > best) { best = v; bj = j2; }
      }
      tokS[tid] = bj;
    }
    __syncthreads();
  }
}

extern "C" void kernel_launch(void* const* d_in, const int* in_sizes, int n_in,
                              void* d_out, int out_size, void* d_ws, size_t ws_size,
                              hipStream_t stream) {
  float* ws = (float*)d_ws;
  int* flag = (int*)(ws + OFF_FLAG);

  detect_dtype<<<1, 64, 0, stream>>>(d_in[3], flag);

  // fp32-world preprocessing (skipped in bf16 world)
  conv_transpose<<<384, 256, 0, stream>>>(d_in[2],  ws + OFF_Z2H,  768, 128, flag);
  conv_transpose<<<192, 256, 0, stream>>>(d_in[6],  ws + OFF_WIH0, 768, 64,  flag);
  conv_transpose<<<768, 256, 0, stream>>>(d_in[7],  ws + OFF_WHH0, 768, 256, flag);
  conv_transpose<<<768, 256, 0, stream>>>(d_in[10], ws + OFF_WIH1, 768, 256, flag);
  conv_transpose<<<768, 256, 0, stream>>>(d_in[11], ws + OFF_WHH1, 768, 256, flag);
  conv_transpose<<<768, 256, 0, stream>>>(d_in[14], ws + OFF_WIH2, 768, 256, flag);
  conv_transpose<<<768, 256, 0, stream>>>(d_in[15], ws + OFF_WHH2, 768, 256, flag);
  conv_transpose<<<64,  256, 0, stream>>>(d_in[4],  ws + OFF_OUTW, 64,  256, flag);
  conv_copy<<<3, 256, 0, stream>>>(d_in[3],  ws + OFF_BZ2H, 768, flag);
  conv_copy<<<3, 256, 0, stream>>>(d_in[8],  ws + OFF_BIH0, 768, flag);
  conv_copy<<<3, 256, 0, stream>>>(d_in[9],  ws + OFF_BHH0, 768, flag);
  conv_copy<<<3, 256, 0, stream>>>(d_in[12], ws + OFF_BIH1, 768, flag);
  conv_copy<<<3, 256, 0, stream>>>(d_in[13], ws + OFF_BHH1, 768, flag);
  conv_copy<<<3, 256, 0, stream>>>(d_in[16], ws + OFF_BIH2, 768, flag);
  conv_copy<<<3, 256, 0, stream>>>(d_in[17], ws + OFF_BHH2, 768, flag);
  conv_copy<<<1, 64,  0, stream>>>(d_in[5],  ws + OFF_OUTB, 64,  flag);

  // fp32 world main (early-exits if bf16)
  moldec_main<<<256, 512, 0, stream>>>(d_in[0], d_in[1], ws, d_out);

  // bf16 MFMA main (early-exits if fp32)
  moldec_mfma<<<256, 512, 0, stream>>>(
      (const bf16*)d_in[0], (const bf16*)d_in[1], (const bf16*)d_in[2],
      (const bf16*)d_in[3], (const bf16*)d_in[4], (const bf16*)d_in[5],
      (const bf16*)d_in[6], (const bf16*)d_in[7], (const bf16*)d_in[8],
      (const bf16*)d_in[9], (const bf16*)d_in[10], (const bf16*)d_in[11],
      (const bf16*)d_in[12], (const bf16*)d_in[13], (const bf16*)d_in[14],
      (const bf16*)d_in[15], (const bf16*)d_in[16], (const bf16*)d_in[17],
      ws, (bf16*)d_out);
}

// Round 5
// 23121.622 us; speedup vs baseline: 1.2049x; 1.2041x over previous
//
#include <hip/hip_runtime.h>
#include <hip/hip_bf16.h>

typedef __bf16 bf16;
typedef __bf16 bf16x8 __attribute__((ext_vector_type(8)));
typedef float  f32x4  __attribute__((ext_vector_type(4)));

#define MFMA16(a,b,c) __builtin_amdgcn_mfma_f32_16x16x32_bf16((a),(b),(c),0,0,0)

#define NSTEP 119
#define BM 16

// ws layout in bf16 elements: packed hi/lo B-fragments per weight matrix.
// Frag block (c,kt) = 1024 bf16: [hi 512][lo 512]; lane reads 8 at lane*8.
#define O_Z2H   0u        // 48 tiles x 4 kt
#define O_WIH0  196608u   // 48 x 2
#define O_WHH0  294912u   // 48 x 8
#define O_WIH1  688128u
#define O_WHH1  1081344u
#define O_WIH2  1474560u
#define O_WHH2  1867776u
#define O_OUTW  2260992u  // 4 x 8

__device__ __forceinline__ f32x4 splat4(float v) { f32x4 r = {v, v, v, v}; return r; }

// fp32 W[Rt*16][KT*32] row-major -> MFMA B-fragments, hi/lo bf16 split.
__global__ void pack2(const float* __restrict__ src, bf16* __restrict__ dst,
                      int Rt, int KT) {
  int idx = blockIdx.x * 256 + threadIdx.x;
  if (idx >= Rt * KT * 64) return;
  int lane = idx & 63, fi = idx >> 6;
  int r15 = lane & 15, q = lane >> 4;
  int c = fi / KT, kt = fi - c * KT;
  const float* s = src + (size_t)(c * 16 + r15) * (KT * 32) + kt * 32 + q * 8;
  bf16* dhi = dst + (size_t)fi * 1024 + lane * 8;
  bf16* dlo = dhi + 512;
  #pragma unroll
  for (int e = 0; e < 8; ++e) {
    float v = s[e];
    bf16 hi = (bf16)v;
    dhi[e] = hi;
    dlo[e] = (bf16)(v - (float)hi);
  }
}

// acc[NT] += A(16xK) x W^T via 3-pass split MFMA. A comps in LDS (ld=Ald),
// B frags in ws at tiles c(t) = cbase + t*cstep.
template<int KT, int NT>
__device__ __forceinline__ void gemm3(f32x4* acc,
    const bf16* __restrict__ A0, const bf16* __restrict__ A1, const int Ald,
    const bf16* __restrict__ BF, const int cbase, const int cstep, const int lane)
{
  const int r15 = lane & 15, q = lane >> 4;
  #pragma unroll
  for (int kt = 0; kt < KT; ++kt) {
    const int ao = r15 * Ald + kt * 32 + q * 8;
    bf16x8 a0 = *(const bf16x8*)(A0 + ao);
    bf16x8 a1 = *(const bf16x8*)(A1 + ao);
    #pragma unroll
    for (int t = 0; t < NT; ++t) {
      const bf16* bp = BF + (size_t)((cbase + t * cstep) * KT + kt) * 1024 + lane * 8;
      bf16x8 b0 = *(const bf16x8*)bp;
      bf16x8 b1 = *(const bf16x8*)(bp + 512);
      acc[t] = MFMA16(a0, b0, acc[t]);
      acc[t] = MFMA16(a1, b0, acc[t]);
      acc[t] = MFMA16(a0, b1, acc[t]);
    }
  }
}

__device__ __forceinline__ void split3(float hv, bf16& c0, bf16& c1, bf16& c2) {
  c0 = (bf16)hv;  float r1 = hv - (float)c0;
  c1 = (bf16)r1;  float r2 = r1 - (float)c1;
  c2 = (bf16)r2;
}

__global__ __launch_bounds__(1024)
void moldec_mfma(const float* __restrict__ z, const float* __restrict__ emb,
                 const float* __restrict__ z2h_b, const float* __restrict__ out_b,
                 const float* __restrict__ bih0, const float* __restrict__ bhh0,
                 const float* __restrict__ bih1, const float* __restrict__ bhh1,
                 const float* __restrict__ bih2, const float* __restrict__ bhh2,
                 const bf16* __restrict__ wsb, float* __restrict__ out)
{
  __shared__ __align__(16) bf16 hS[3][3][16][264];  // [layer][comp][row][j]
  __shared__ __align__(16) bf16 xS[2][16][72];
  __shared__ __align__(16) bf16 zS[2][16][136];
  __shared__ float logS[16][66];
  __shared__ int tokS[16];

  const int tid  = threadIdx.x;
  const int wave = tid >> 6;
  const int lane = tid & 63;
  const int q    = lane >> 4;
  const int r15  = lane & 15;
  const int b0   = blockIdx.x * BM;
  const int j0   = wave * 16;   // wave owns neurons [j0, j0+16)

  // ---- stage z (fp32 -> 2-comp bf16) ----
  if (tid < 512) {
    const int m = tid >> 5, c4 = (tid & 31) * 4;
    float4 v = *(const float4*)(z + (size_t)(b0 + m) * 128 + c4);
    const float vv[4] = {v.x, v.y, v.z, v.w};
    #pragma unroll
    for (int e = 0; e < 4; ++e) {
      bf16 hi = (bf16)vv[e];
      zS[0][m][c4 + e] = hi;
      zS[1][m][c4 + e] = (bf16)(vv[e] - (float)hi);
    }
    if (tid < 16) tokS[tid] = 1;
  }
  __syncthreads();

  // ---- h0 = tanh(z @ z2h_w.T + b); wave handles col-tiles wave*3..+2 ----
  {
    f32x4 acc[3];
    #pragma unroll
    for (int t = 0; t < 3; ++t)
      acc[t] = splat4(z2h_b[(wave * 3 + t) * 16 + r15]);
    gemm3<4, 3>(acc, &zS[0][0][0], &zS[1][0][0], 136, wsb + O_Z2H, wave * 3, 1, lane);
    #pragma unroll
    for (int t = 0; t < 3; ++t) {
      const int col = (wave * 3 + t) * 16 + r15;
      const int lay = col >> 8, j = col & 255;
      #pragma unroll
      for (int r = 0; r < 4; ++r) {
        const int m = q * 4 + r;
        float hv = tanhf(acc[t][r]);
        bf16 c0, c1, c2;
        split3(hv, c0, c1, c2);
        hS[lay][0][m][j] = c0; hS[lay][1][m][j] = c1; hS[lay][2][m][j] = c2;
      }
    }
  }
  __syncthreads();

  for (int step = 0; step < NSTEP; ++step) {
    // ---- x = emb[tok] (fp32 -> 2-comp bf16) ----
    if (tid < 128) {
      const int m = tid >> 3, e8 = (tid & 7) * 8;
      const int tk = tokS[m];
      float4 v0 = *(const float4*)(emb + (size_t)tk * 64 + e8);
      float4 v1 = *(const float4*)(emb + (size_t)tk * 64 + e8 + 4);
      const float vv[8] = {v0.x, v0.y, v0.z, v0.w, v1.x, v1.y, v1.z, v1.w};
      #pragma unroll
      for (int e = 0; e < 8; ++e) {
        bf16 hi = (bf16)vv[e];
        xS[0][m][e8 + e] = hi;
        xS[1][m][e8 + e] = (bf16)(vv[e] - (float)hi);
      }
    }
    __syncthreads();

    // ================= 3 GRU layers =================
    #pragma unroll 1
    for (int layer = 0; layer < 3; ++layer) {
      const float* bih = layer == 0 ? bih0 : (layer == 1 ? bih1 : bih2);
      const float* bhh = layer == 0 ? bhh0 : (layer == 1 ? bhh1 : bhh2);
      f32x4 ai[3], ah[3];
      #pragma unroll
      for (int t = 0; t < 3; ++t) {
        ai[t] = splat4(bih[t * 256 + j0 + r15]);
        ah[t] = splat4(bhh[t * 256 + j0 + r15]);
      }
      if (layer == 0) {
        gemm3<2, 3>(ai, &xS[0][0][0], &xS[1][0][0], 72, wsb + O_WIH0, wave, 16, lane);
        gemm3<8, 3>(ah, &hS[0][0][0][0], &hS[0][1][0][0], 264, wsb + O_WHH0, wave, 16, lane);
      } else if (layer == 1) {
        gemm3<8, 3>(ai, &hS[0][0][0][0], &hS[0][1][0][0], 264, wsb + O_WIH1, wave, 16, lane);
        gemm3<8, 3>(ah, &hS[1][0][0][0], &hS[1][1][0][0], 264, wsb + O_WHH1, wave, 16, lane);
      } else {
        gemm3<8, 3>(ai, &hS[1][0][0][0], &hS[1][1][0][0], 264, wsb + O_WIH2, wave, 16, lane);
        gemm3<8, 3>(ah, &hS[2][0][0][0], &hS[2][1][0][0], 264, wsb + O_WHH2, wave, 16, lane);
      }
      __syncthreads();   // all reads of h[layer] complete before update

      const int j = j0 + r15;
      #pragma unroll
      for (int r = 0; r < 4; ++r) {
        const int m = q * 4 + r;
        float rg = 1.f / (1.f + expf(-(ai[0][r] + ah[0][r])));
        float zg = 1.f / (1.f + expf(-(ai[1][r] + ah[1][r])));
        float ng = tanhf(ai[2][r] + rg * ah[2][r]);
        float hp = (float)hS[layer][0][m][j] + (float)hS[layer][1][m][j]
                 + (float)hS[layer][2][m][j];
        float hv = (1.f - zg) * ng + zg * hp;
        bf16 c0, c1, c2;
        split3(hv, c0, c1, c2);
        hS[layer][0][m][j] = c0; hS[layer][1][m][j] = c1; hS[layer][2][m][j] = c2;
      }
      __syncthreads();
    }

    // ---- logits: waves 0-3, one 16-col tile each ----
    if (wave < 4) {
      const int col = wave * 16 + r15;
      f32x4 acc = splat4(out_b[col]);
      gemm3<8, 1>(&acc, &hS[2][0][0][0], &hS[2][1][0][0], 264, wsb + O_OUTW, wave, 0, lane);
      #pragma unroll
      for (int r = 0; r < 4; ++r) {
        const int m = q * 4 + r;
        logS[m][col] = acc[r];
        out[((size_t)(b0 + m) * NSTEP + step) * 64 + col] = acc[r];
      }
    }
    __syncthreads();

    // ---- argmax (first-max semantics) ----
    if (tid < 16) {
      float best = logS[tid][0]; int bj = 0;
      for (int j2 = 1; j2 < 64; ++j2) {
        float v = logS[tid][j2];
        if (v > best) { best = v; bj = j2; }
      }
      tokS[tid] = bj;
    }
    __syncthreads();
  }
}

extern "C" void kernel_launch(void* const* d_in, const int* in_sizes, int n_in,
                              void* d_out, int out_size, void* d_ws, size_t ws_size,
                              hipStream_t stream) {
  bf16* wsb = (bf16*)d_ws;

  pack2<<<48, 256, 0, stream>>>((const float*)d_in[2],  wsb + O_Z2H,  48, 4);
  pack2<<<24, 256, 0, stream>>>((const float*)d_in[6],  wsb + O_WIH0, 48, 2);
  pack2<<<96, 256, 0, stream>>>((const float*)d_in[7],  wsb + O_WHH0, 48, 8);
  pack2<<<96, 256, 0, stream>>>((const float*)d_in[10], wsb + O_WIH1, 48, 8);
  pack2<<<96, 256, 0, stream>>>((const float*)d_in[11], wsb + O_WHH1, 48, 8);
  pack2<<<96, 256, 0, stream>>>((const float*)d_in[14], wsb + O_WIH2, 48, 8);
  pack2<<<96, 256, 0, stream>>>((const float*)d_in[15], wsb + O_WHH2, 48, 8);
  pack2<<<8,  256, 0, stream>>>((const float*)d_in[4],  wsb + O_OUTW, 4,  8);

  moldec_mfma<<<256, 1024, 0, stream>>>(
      (const float*)d_in[0],  (const float*)d_in[1],
      (const float*)d_in[3],  (const float*)d_in[5],
      (const float*)d_in[8],  (const float*)d_in[9],
      (const float*)d_in[12], (const float*)d_in[13],
      (const float*)d_in[16], (const float*)d_in[17],
      wsb, (float*)d_out);
}